// Round 3
// baseline (172.439 us; speedup 1.0000x reference)
//
#include <hip/hip_runtime.h>
#include <math.h>

#define NB 32768
#define NC 1000
#define ND 512
#define NCTILES 16          // 16 tiles x 64 classes = 1024 padded classes
#define PROWS 1024
#define LOG2E 1.4426950408889634f
#define LN2 0.6931471805599453f
#define S2 14.426950408889634f   // (1/T) * log2(e) = 10 * LOG2E
#define NBUCKET 64

typedef __attribute__((ext_vector_type(8))) short short8;
typedef __attribute__((ext_vector_type(4))) float f32x4;
typedef __attribute__((ext_vector_type(16))) float f32x16;

__device__ __forceinline__ float fexp2(float x) {
    float r; asm("v_exp_f32 %0, %1" : "=v"(r) : "v"(x)); return r;
}
__device__ __forceinline__ float flog2(float x) {
    float r; asm("v_log_f32 %0, %1" : "=v"(r) : "v"(x)); return r;
}
__device__ __forceinline__ unsigned short bf16_rne(float f) {
    unsigned int u = __builtin_bit_cast(unsigned int, f);
    u += 0x7FFFu + ((u >> 16) & 1u);
    return (unsigned short)(u >> 16);
}
__device__ __forceinline__ short8 pack8(const float* v) {
    short8 s;
#pragma unroll
    for (int i = 0; i < 8; ++i) s[i] = (short)bf16_rne(v[i]);
    return s;
}

// ---------------- normalize prototypes -> bf16 [PROWS][ND] ----------------
__global__ __launch_bounds__(256) void norm_protos(const float* __restrict__ pro,
                                                   unsigned short* __restrict__ pbf) {
    const int row = blockIdx.x, t = threadIdx.x;
    unsigned int* dst = (unsigned int*)(pbf + (size_t)row * ND);
    if (row >= NC) { dst[t] = 0u; return; }  // zero pad rows (uniform per block)
    const float* rp = pro + (size_t)row * ND;
    const float x0 = rp[2 * t], x1 = rp[2 * t + 1];
    float ss = x0 * x0 + x1 * x1;
#pragma unroll
    for (int o = 1; o < 64; o <<= 1) ss += __shfl_xor(ss, o, 64);
    __shared__ float part[4];
    if ((t & 63) == 0) part[t >> 6] = ss;
    __syncthreads();
    const float nrm = sqrtf(part[0] + part[1] + part[2] + part[3]);
    const float sc = 1.0f / fmaxf(nrm, 1e-12f);
    dst[t] = (unsigned int)bf16_rne(x0 * sc) | ((unsigned int)bf16_rne(x1 * sc) << 16);
}

// Stage a 64-class x 512-k bf16 tile: wave `wid` stages subtile sub=wid.
// LDS layout (short8 units): idx = ks*128 + sub*64 + lane  -> linear per-wave dest.
// Per q: src += 32B (imm-offset-foldable), dst += 2048B.
__device__ __forceinline__ void stage64(const unsigned short* __restrict__ pbf,
                                        short8* buf, int ct, int wid, int lane) {
    const unsigned short* src =
        pbf + (size_t)(ct * 64 + wid * 32 + (lane & 31)) * ND + 8 * (lane >> 5);
    short8* dst = buf + wid * 64 + lane;
#pragma unroll
    for (int q = 0; q < 32; ++q) {
        __builtin_amdgcn_global_load_lds(
            (const __attribute__((address_space(1))) unsigned int*)(src + 16 * q),
            (__attribute__((address_space(3))) unsigned int*)(dst + 128 * q), 16, 0, 0);
    }
}

// ---------------- simloss: fused GEMM (32x32x16) + online logsumexp ----------------
// Swapped MFMA: D = P_tile(A, 32cls x 16k) * F^T(B, 16k x 32rows).
// D layout (m74/m101): col=lane&31 = feature row, class = (r&3)+8*(r>>2)+4*(lane>>5).
// Wave owns 64 rows (2 row-groups); tile = 64 classes (2 subtiles) -> 2x2 acc grid.
__global__ __launch_bounds__(128, 1) void simloss_kernel(const float* __restrict__ feat,
                                                         const int* __restrict__ labels,
                                                         const unsigned short* __restrict__ pbf,
                                                         float* __restrict__ buckets) {
    __shared__ short8 lds[2][4096];  // 2 x 64 KiB double buffer
    __shared__ float wsum[2];
    const int t = threadIdx.x;
    const int wid = t >> 6, lane = t & 63;
    const int l31 = lane & 31, h = lane >> 5;
    const int rowbase = blockIdx.x * 128 + wid * 64;

    stage64(pbf, lds[0], 0, wid, lane);  // tile 0 in flight during feature load

    // Feature fragments: bf[rg][ks] holds feat[row][16*ks + 8*h + e], e=0..7
    short8 bf0[32], bf1[32];
    {
        const float* f0 = feat + (size_t)(rowbase + l31) * ND + 8 * h;
        const float* f1 = feat + (size_t)(rowbase + 32 + l31) * ND + 8 * h;
#pragma unroll
        for (int ks = 0; ks < 32; ++ks) {
            float v[8];
            float4 a = *(const float4*)(f0 + 16 * ks);
            float4 b = *(const float4*)(f0 + 16 * ks + 4);
            v[0]=a.x; v[1]=a.y; v[2]=a.z; v[3]=a.w; v[4]=b.x; v[5]=b.y; v[6]=b.z; v[7]=b.w;
            bf0[ks] = pack8(v);
            a = *(const float4*)(f1 + 16 * ks);
            b = *(const float4*)(f1 + 16 * ks + 4);
            v[0]=a.x; v[1]=a.y; v[2]=a.z; v[3]=a.w; v[4]=b.x; v[5]=b.y; v[6]=b.z; v[7]=b.w;
            bf1[ks] = pack8(v);
        }
    }
    int lab0 = labels[rowbase + l31];
    int lab1 = labels[rowbase + 32 + l31];
    lab0 = lab0 < 0 ? 0 : (lab0 > NC - 1 ? NC - 1 : lab0);
    lab1 = lab1 < 0 ? 0 : (lab1 > NC - 1 ? NC - 1 : lab1);

    float m0 = -INFINITY, ls0 = 0.f, lv0 = 0.f;
    float m1 = -INFINITY, ls1 = 0.f, lv1 = 0.f;

    __syncthreads();  // tile 0 resident (vmcnt drained at barrier)

    for (int ct = 0; ct < NCTILES; ++ct) {
        const short8* cur = lds[ct & 1];
        if (ct + 1 < NCTILES) stage64(pbf, lds[(ct + 1) & 1], ct + 1, wid, lane);

        f32x16 a00 = {}, a01 = {}, a10 = {}, a11 = {};  // [rg][sub]
#pragma unroll
        for (int ks = 0; ks < 32; ++ks) {
            const short8 p0 = cur[ks * 128 + lane];        // sub 0
            const short8 p1 = cur[ks * 128 + 64 + lane];   // sub 1
            a00 = __builtin_amdgcn_mfma_f32_32x32x16_bf16(p0, bf0[ks], a00, 0, 0, 0);
            a10 = __builtin_amdgcn_mfma_f32_32x32x16_bf16(p0, bf1[ks], a10, 0, 0, 0);
            a01 = __builtin_amdgcn_mfma_f32_32x32x16_bf16(p1, bf0[ks], a01, 0, 0, 0);
            a11 = __builtin_amdgcn_mfma_f32_32x32x16_bf16(p1, bf1[ks], a11, 0, 0, 0);
        }

        const int cbase = ct * 64 + 4 * h;
        // ---- rg0 ----
        {
            float tmax = -INFINITY;
#pragma unroll
            for (int r = 0; r < 16; ++r) {
                const int c0 = cbase + (r & 3) + 8 * (r >> 2);
                const float x0 = (c0 < NC) ? a00[r] * S2 : -INFINITY;
                const float x1 = (c0 + 32 < NC) ? a01[r] * S2 : -INFINITY;
                tmax = fmaxf(tmax, fmaxf(x0, x1));
            }
            const float mn = fmaxf(m0, tmax);
            ls0 *= fexp2(m0 - mn);  // =1 if no new max; =0 on first tile
            m0 = mn;
            float add = 0.f;
#pragma unroll
            for (int r = 0; r < 16; ++r) {
                const int c0 = cbase + (r & 3) + 8 * (r >> 2);
                const float x0 = (c0 < NC) ? a00[r] * S2 : -INFINITY;
                const float x1 = (c0 + 32 < NC) ? a01[r] * S2 : -INFINITY;
                lv0 += (c0 == lab0) ? x0 : 0.f;
                lv0 += (c0 + 32 == lab0) ? x1 : 0.f;
                add += fexp2(x0 - m0) + fexp2(x1 - m0);
            }
            ls0 += add;
        }
        // ---- rg1 ----
        {
            float tmax = -INFINITY;
#pragma unroll
            for (int r = 0; r < 16; ++r) {
                const int c0 = cbase + (r & 3) + 8 * (r >> 2);
                const float x0 = (c0 < NC) ? a10[r] * S2 : -INFINITY;
                const float x1 = (c0 + 32 < NC) ? a11[r] * S2 : -INFINITY;
                tmax = fmaxf(tmax, fmaxf(x0, x1));
            }
            const float mn = fmaxf(m1, tmax);
            ls1 *= fexp2(m1 - mn);
            m1 = mn;
            float add = 0.f;
#pragma unroll
            for (int r = 0; r < 16; ++r) {
                const int c0 = cbase + (r & 3) + 8 * (r >> 2);
                const float x0 = (c0 < NC) ? a10[r] * S2 : -INFINITY;
                const float x1 = (c0 + 32 < NC) ? a11[r] * S2 : -INFINITY;
                lv1 += (c0 == lab1) ? x0 : 0.f;
                lv1 += (c0 + 32 == lab1) ? x1 : 0.f;
                add += fexp2(x0 - m1) + fexp2(x1 - m1);
            }
            ls1 += add;
        }
        __syncthreads();  // all waves done with cur; next tile resident
    }

    // Merge h-halves: lanes l and l^32 hold the same row, disjoint class sets
    {
        const float mo = __shfl_xor(m0, 32, 64), lo = __shfl_xor(ls0, 32, 64);
        lv0 += __shfl_xor(lv0, 32, 64);
        const float mm = fmaxf(m0, mo);
        ls0 = ls0 * fexp2(m0 - mm) + lo * fexp2(mo - mm);
        m0 = mm;
    }
    {
        const float mo = __shfl_xor(m1, 32, 64), lo = __shfl_xor(ls1, 32, 64);
        lv1 += __shfl_xor(lv1, 32, 64);
        const float mm = fmaxf(m1, mo);
        ls1 = ls1 * fexp2(m1 - mm) + lo * fexp2(mo - mm);
        m1 = mm;
    }
    const float row0 = (m0 + flog2(ls0) - lv0) * LN2;  // replicated on 2 lanes
    const float row1 = (m1 + flog2(ls1) - lv1) * LN2;
    float mine = (row0 + row1) * (0.5f / (float)NB);
#pragma unroll
    for (int o = 1; o < 64; o <<= 1) mine += __shfl_xor(mine, o, 64);
    if (lane == 0) wsum[wid] = mine;
    __syncthreads();
    if (t == 0)
        atomicAdd(buckets + (blockIdx.x & (NBUCKET - 1)) * 16, wsum[0] + wsum[1]);
}

// ---------------- cross-entropy over logits ----------------
__global__ __launch_bounds__(256) void ce_kernel(const float* __restrict__ logits,
                                                 const int* __restrict__ labels,
                                                 float* __restrict__ buckets) {
    __shared__ float wsum[4];
    const int t = threadIdx.x, wid = t >> 6, lane = t & 63;
    const int wgid = blockIdx.x * 4 + wid;  // 4096 waves, 8 rows each
    float local = 0.f;

    for (int row = wgid; row < NB; row += 4096) {
        const float* rp = logits + (size_t)row * NC;
        float x[16];
#pragma unroll
        for (int j = 0; j < 4; ++j) {
            const int c0 = lane * 4 + j * 256;
            if (c0 < NC) {
                const float4 v = *(const float4*)(rp + c0);
                x[4 * j] = v.x * LOG2E; x[4 * j + 1] = v.y * LOG2E;
                x[4 * j + 2] = v.z * LOG2E; x[4 * j + 3] = v.w * LOG2E;
            } else {
                x[4 * j] = x[4 * j + 1] = x[4 * j + 2] = x[4 * j + 3] = -INFINITY;
            }
        }
        float m = -INFINITY;
#pragma unroll
        for (int i = 0; i < 16; ++i) m = fmaxf(m, x[i]);
#pragma unroll
        for (int o = 1; o < 64; o <<= 1) m = fmaxf(m, __shfl_xor(m, o, 64));
        float s = 0.f;
#pragma unroll
        for (int i = 0; i < 16; ++i) s += fexp2(x[i] - m);
#pragma unroll
        for (int o = 1; o < 64; o <<= 1) s += __shfl_xor(s, o, 64);
        int lab = labels[row];
        lab = lab < 0 ? 0 : (lab > NC - 1 ? NC - 1 : lab);
        local += (m + flog2(s)) * LN2 - rp[lab];  // identical on all lanes
    }
    if (lane == 0) wsum[wid] = local;
    __syncthreads();
    if (t == 0)
        atomicAdd(buckets + (blockIdx.x & (NBUCKET - 1)) * 16,
                  (wsum[0] + wsum[1] + wsum[2] + wsum[3]) * (1.0f / (float)NB));
}

// ---------------- prototype Gram exp-sum (off-diagonal); pbf is L2-resident ----------------
__global__ __launch_bounds__(256) void gram_kernel(const unsigned short* __restrict__ pbf,
                                                   float* __restrict__ buckets) {
    __shared__ float wsum[4];
    const int t = threadIdx.x;
    const int wid = t >> 6, lane = t & 63;
    const int r16 = lane & 15, g = lane >> 4;
    const int ct = blockIdx.y;                           // class tile 0..62 (16-wide)
    const int irow = blockIdx.x * 64 + wid * 16 + r16;   // 0..1023 (pad rows zero)

    short8 bfrag[16], afrag[16];
    const unsigned short* ip = pbf + (size_t)irow * ND + 8 * g;
    const unsigned short* ap = pbf + (size_t)(ct * 16 + r16) * ND + 8 * g;
#pragma unroll
    for (int kk = 0; kk < 16; ++kk) {
        bfrag[kk] = *(const short8*)(ip + 32 * kk);
        afrag[kk] = *(const short8*)(ap + 32 * kk);
    }
    f32x4 dacc = {0.f, 0.f, 0.f, 0.f};
#pragma unroll
    for (int kk = 0; kk < 16; ++kk)
        dacc = __builtin_amdgcn_mfma_f32_16x16x32_bf16(afrag[kk], bfrag[kk], dacc, 0, 0, 0);

    float s = 0.f;
    if (irow < NC) {
        const int cbase = ct * 16 + g * 4;
#pragma unroll
        for (int rI = 0; rI < 4; ++rI) {
            const int j = cbase + rI;
            if (j < NC && j != irow) s += fexp2(dacc[rI] * LOG2E);
        }
    }
#pragma unroll
    for (int o = 1; o < 64; o <<= 1) s += __shfl_xor(s, o, 64);
    if (lane == 0) wsum[wid] = s;
    __syncthreads();
    if (t == 0)
        atomicAdd(buckets + ((blockIdx.x + 16 * blockIdx.y) & (NBUCKET - 1)) * 16,
                  wsum[0] + wsum[1] + wsum[2] + wsum[3]);
}

// ---------------- final combine: sum buckets ----------------
__global__ void combine_kernel(const float* __restrict__ a, float* __restrict__ out) {
    const int t = threadIdx.x;  // 64 threads
    float s = a[t * 16], c = a[1024 + t * 16], gr = a[2048 + t * 16];
#pragma unroll
    for (int o = 1; o < 64; o <<= 1) {
        s += __shfl_xor(s, o, 64);
        c += __shfl_xor(c, o, 64);
        gr += __shfl_xor(gr, o, 64);
    }
    if (t == 0) out[0] = s + c + logf(gr) * (1.0f / (float)NC);
}

extern "C" void kernel_launch(void* const* d_in, const int* in_sizes, int n_in,
                              void* d_out, int out_size, void* d_ws, size_t ws_size,
                              hipStream_t stream) {
    const float* feat   = (const float*)d_in[0];  // [32768,512]
    const float* logits = (const float*)d_in[1];  // [32768,1000]
    const int*   labels = (const int*)d_in[2];    // [32768]
    const float* pro    = (const float*)d_in[3];  // [1000,512]
    float* out = (float*)d_out;

    float* acc = (float*)d_ws;  // buckets: [0]=sim, [1024]=ce, [2048]=gram (stride-16 floats)
    unsigned short* pbf = (unsigned short*)((char*)d_ws + 16384);  // [1024][512] bf16, 1 MiB

    hipMemsetAsync(d_ws, 0, 3072 * sizeof(float), stream);
    hipLaunchKernelGGL(norm_protos,    dim3(PROWS),      dim3(256), 0, stream, pro, pbf);
    hipLaunchKernelGGL(simloss_kernel, dim3(NB / 128),   dim3(128), 0, stream, feat, labels, pbf, acc);
    hipLaunchKernelGGL(ce_kernel,      dim3(1024),       dim3(256), 0, stream, logits, labels, acc + 1024);
    hipLaunchKernelGGL(gram_kernel,    dim3(16, 63),     dim3(256), 0, stream, pbf, acc + 2048);
    hipLaunchKernelGGL(combine_kernel, dim3(1),          dim3(64),  0, stream, acc, out);
}

// Round 4
// 147.774 us; speedup vs baseline: 1.1669x; 1.1669x over previous
//
#include <hip/hip_runtime.h>
#include <math.h>

#define NB 32768
#define NC 1000
#define ND 512
#define NTILES 63          // 63*16 = 1008 >= 1000 class columns
#define PROWS 1024
#define LOG2E 1.4426950408889634f
#define LN2 0.6931471805599453f
#define S2 14.426950408889634f   // (1/T) * log2(e)
#define NBUCKET 64

typedef __attribute__((ext_vector_type(8))) short short8;
typedef __attribute__((ext_vector_type(4))) float f32x4;

__device__ __forceinline__ float fexp2(float x) {
    float r; asm("v_exp_f32 %0, %1" : "=v"(r) : "v"(x)); return r;
}
__device__ __forceinline__ float flog2(float x) {
    float r; asm("v_log_f32 %0, %1" : "=v"(r) : "v"(x)); return r;
}
__device__ __forceinline__ unsigned short bf16_rne(float f) {
    unsigned int u = __builtin_bit_cast(unsigned int, f);
    u += 0x7FFFu + ((u >> 16) & 1u);
    return (unsigned short)(u >> 16);
}
__device__ __forceinline__ short8 pack8f(float4 a, float4 b) {
    short8 s;
    s[0] = (short)bf16_rne(a.x); s[1] = (short)bf16_rne(a.y);
    s[2] = (short)bf16_rne(a.z); s[3] = (short)bf16_rne(a.w);
    s[4] = (short)bf16_rne(b.x); s[5] = (short)bf16_rne(b.y);
    s[6] = (short)bf16_rne(b.z); s[7] = (short)bf16_rne(b.w);
    return s;
}

// ---------------- normalize prototypes -> bf16 [PROWS][ND] ----------------
__global__ __launch_bounds__(256) void norm_protos(const float* __restrict__ pro,
                                                   unsigned short* __restrict__ pbf) {
    const int row = blockIdx.x, t = threadIdx.x;
    unsigned int* dst = (unsigned int*)(pbf + (size_t)row * ND);
    if (row >= NC) { dst[t] = 0u; return; }  // zero pad rows (uniform per block)
    const float* rp = pro + (size_t)row * ND;
    const float x0 = rp[2 * t], x1 = rp[2 * t + 1];
    float ss = x0 * x0 + x1 * x1;
#pragma unroll
    for (int o = 1; o < 64; o <<= 1) ss += __shfl_xor(ss, o, 64);
    __shared__ float part[4];
    if ((t & 63) == 0) part[t >> 6] = ss;
    __syncthreads();
    const float nrm = sqrtf(part[0] + part[1] + part[2] + part[3]);
    const float sc = 1.0f / fmaxf(nrm, 1e-12f);
    dst[t] = (unsigned int)bf16_rne(x0 * sc) | ((unsigned int)bf16_rne(x1 * sc) << 16);
}

// Stage one 16-class x 512-k bf16 tile (16 KiB) into LDS in fragment order
// [kk][g][r]; dest per wave = uniform base + lane*16 (global_load_lds-legal).
__device__ __forceinline__ void stage_tile(const unsigned short* __restrict__ pbf,
                                           short8* buf, int ct, int t) {
#pragma unroll
    for (int q = 0; q < 4; ++q) {
        const int id = t + 256 * q;
        const int rr = id & 15, gg = (id >> 4) & 3, kk = id >> 6;
        const unsigned short* src = pbf + (size_t)(ct * 16 + rr) * ND + 32 * kk + 8 * gg;
        __builtin_amdgcn_global_load_lds(
            (const __attribute__((address_space(1))) unsigned int*)src,
            (__attribute__((address_space(3))) unsigned int*)(buf + id), 16, 0, 0);
    }
}

// ---------------- simloss: fused GEMM + online logsumexp ----------------
// 16x16x32 MFMA, swapped operands: D = P_tile(A) * F^T(B).
// D layout (m89): col=lane&15 = feature row, class = (lane>>4)*4 + reg.
// Wave holds 32 feature rows (2 row-groups of 16) -> each A-read feeds 2 MFMAs.
__global__ __launch_bounds__(256, 2) void simloss_kernel(const float* __restrict__ feat,
                                                         const int* __restrict__ labels,
                                                         const unsigned short* __restrict__ pbf,
                                                         float* __restrict__ buckets) {
    __shared__ short8 lds[2][1024];  // 2 x 16 KiB double buffer
    __shared__ float wsum[4];
    const int t = threadIdx.x;
    const int wid = t >> 6, lane = t & 63;
    const int r16 = lane & 15, g = lane >> 4;
    const int rowbase = blockIdx.x * 128 + wid * 32;

    stage_tile(pbf, lds[0], 0, t);  // tile 0 in flight during feature load

    // Feature fragments for 2 row-groups: bf*[kk] = feat[row][32*kk + 8*g .. +8]
    short8 bf0[16], bf1[16];
    {
        const float* f0 = feat + (size_t)(rowbase + r16) * ND + 8 * g;
        const float* f1 = f0 + 16 * ND;
#pragma unroll
        for (int kk = 0; kk < 16; ++kk) {
            bf0[kk] = pack8f(*(const float4*)(f0 + 32 * kk), *(const float4*)(f0 + 32 * kk + 4));
            bf1[kk] = pack8f(*(const float4*)(f1 + 32 * kk), *(const float4*)(f1 + 32 * kk + 4));
        }
    }
    int lab0 = labels[rowbase + r16];
    int lab1 = labels[rowbase + 16 + r16];
    lab0 = lab0 < 0 ? 0 : (lab0 > NC - 1 ? NC - 1 : lab0);
    lab1 = lab1 < 0 ? 0 : (lab1 > NC - 1 ? NC - 1 : lab1);

    float m0 = -INFINITY, ls0 = 0.f, lv0 = 0.f;
    float m1 = -INFINITY, ls1 = 0.f, lv1 = 0.f;

    __syncthreads();  // tile 0 resident

    for (int ct = 0; ct < NTILES; ++ct) {
        const short8* cur = lds[ct & 1];
        if (ct + 1 < NTILES) stage_tile(pbf, lds[(ct + 1) & 1], ct + 1, t);

        f32x4 a0 = {0.f, 0.f, 0.f, 0.f}, a1 = {0.f, 0.f, 0.f, 0.f};
#pragma unroll
        for (int kk = 0; kk < 16; ++kk) {
            const short8 af = cur[kk * 64 + lane];
            a0 = __builtin_amdgcn_mfma_f32_16x16x32_bf16(af, bf0[kk], a0, 0, 0, 0);
            a1 = __builtin_amdgcn_mfma_f32_16x16x32_bf16(af, bf1[kk], a1, 0, 0, 0);
        }

        const int cbase = ct * 16 + g * 4;
        // ---- row-group 0 ----
        {
            float x[4];
#pragma unroll
            for (int rI = 0; rI < 4; ++rI) {
                const float v = a0[rI] * S2;
                x[rI] = (cbase + rI < NC) ? v : -INFINITY;   // only bites at ct==62
                lv0 += (cbase + rI == lab0) ? v : 0.f;
            }
            const float tmax = fmaxf(fmaxf(x[0], x[1]), fmaxf(x[2], x[3]));
            const float mn = fmaxf(m0, tmax);
            ls0 *= fexp2(m0 - mn);  // =1 if no new max; =0 on first tile
            m0 = mn;
            ls0 += fexp2(x[0] - mn) + fexp2(x[1] - mn) + fexp2(x[2] - mn) + fexp2(x[3] - mn);
        }
        // ---- row-group 1 ----
        {
            float x[4];
#pragma unroll
            for (int rI = 0; rI < 4; ++rI) {
                const float v = a1[rI] * S2;
                x[rI] = (cbase + rI < NC) ? v : -INFINITY;
                lv1 += (cbase + rI == lab1) ? v : 0.f;
            }
            const float tmax = fmaxf(fmaxf(x[0], x[1]), fmaxf(x[2], x[3]));
            const float mn = fmaxf(m1, tmax);
            ls1 *= fexp2(m1 - mn);
            m1 = mn;
            ls1 += fexp2(x[0] - mn) + fexp2(x[1] - mn) + fexp2(x[2] - mn) + fexp2(x[3] - mn);
        }
        __syncthreads();  // all waves done with cur; next tile resident
    }

    // Merge the 4 lane-groups (g=0..3) holding the same feature rows
#pragma unroll
    for (int o = 16; o <= 32; o <<= 1) {
        {
            const float mo = __shfl_xor(m0, o, 64), lo = __shfl_xor(ls0, o, 64);
            lv0 += __shfl_xor(lv0, o, 64);
            const float mm = fmaxf(m0, mo);
            ls0 = ls0 * fexp2(m0 - mm) + lo * fexp2(mo - mm);
            m0 = mm;
        }
        {
            const float mo = __shfl_xor(m1, o, 64), lo = __shfl_xor(ls1, o, 64);
            lv1 += __shfl_xor(lv1, o, 64);
            const float mm = fmaxf(m1, mo);
            ls1 = ls1 * fexp2(m1 - mm) + lo * fexp2(mo - mm);
            m1 = mm;
        }
    }
    const float row0 = (m0 + flog2(ls0) - lv0) * LN2;  // replicated on 4 lanes
    const float row1 = (m1 + flog2(ls1) - lv1) * LN2;
    float mine = (row0 + row1) * (1.0f / (4.0f * (float)NB));
#pragma unroll
    for (int o = 1; o < 64; o <<= 1) mine += __shfl_xor(mine, o, 64);
    if (lane == 0) wsum[wid] = mine;
    __syncthreads();
    if (t == 0)
        atomicAdd(buckets + (blockIdx.x & (NBUCKET - 1)) * 16,
                  wsum[0] + wsum[1] + wsum[2] + wsum[3]);
}

// ---------------- cross-entropy over logits ----------------
__global__ __launch_bounds__(256) void ce_kernel(const float* __restrict__ logits,
                                                 const int* __restrict__ labels,
                                                 float* __restrict__ buckets) {
    __shared__ float wsum[4];
    const int t = threadIdx.x, wid = t >> 6, lane = t & 63;
    const int wgid = blockIdx.x * 4 + wid;  // 4096 waves, 8 rows each
    float local = 0.f;

    for (int row = wgid; row < NB; row += 4096) {
        const float* rp = logits + (size_t)row * NC;
        float x[16];
#pragma unroll
        for (int j = 0; j < 4; ++j) {
            const int c0 = lane * 4 + j * 256;
            if (c0 < NC) {
                const float4 v = *(const float4*)(rp + c0);
                x[4 * j] = v.x * LOG2E; x[4 * j + 1] = v.y * LOG2E;
                x[4 * j + 2] = v.z * LOG2E; x[4 * j + 3] = v.w * LOG2E;
            } else {
                x[4 * j] = x[4 * j + 1] = x[4 * j + 2] = x[4 * j + 3] = -INFINITY;
            }
        }
        float m = -INFINITY;
#pragma unroll
        for (int i = 0; i < 16; ++i) m = fmaxf(m, x[i]);
#pragma unroll
        for (int o = 1; o < 64; o <<= 1) m = fmaxf(m, __shfl_xor(m, o, 64));
        float s = 0.f;
#pragma unroll
        for (int i = 0; i < 16; ++i) s += fexp2(x[i] - m);
#pragma unroll
        for (int o = 1; o < 64; o <<= 1) s += __shfl_xor(s, o, 64);
        int lab = labels[row];
        lab = lab < 0 ? 0 : (lab > NC - 1 ? NC - 1 : lab);
        local += (m + flog2(s)) * LN2 - rp[lab];  // identical on all lanes
    }
    if (lane == 0) wsum[wid] = local;
    __syncthreads();
    if (t == 0)
        atomicAdd(buckets + (blockIdx.x & (NBUCKET - 1)) * 16,
                  (wsum[0] + wsum[1] + wsum[2] + wsum[3]) * (1.0f / (float)NB));
}

// ---------------- prototype Gram exp-sum (off-diagonal); pbf is L2-resident ----------------
__global__ __launch_bounds__(256) void gram_kernel(const unsigned short* __restrict__ pbf,
                                                   float* __restrict__ buckets) {
    __shared__ float wsum[4];
    const int t = threadIdx.x;
    const int wid = t >> 6, lane = t & 63;
    const int r16 = lane & 15, g = lane >> 4;
    const int ct = blockIdx.y;                           // class tile 0..62 (16-wide)
    const int irow = blockIdx.x * 64 + wid * 16 + r16;   // 0..1023 (pad rows zero)

    short8 bfrag[16], afrag[16];
    const unsigned short* ip = pbf + (size_t)irow * ND + 8 * g;
    const unsigned short* ap = pbf + (size_t)(ct * 16 + r16) * ND + 8 * g;
#pragma unroll
    for (int kk = 0; kk < 16; ++kk) {
        bfrag[kk] = *(const short8*)(ip + 32 * kk);
        afrag[kk] = *(const short8*)(ap + 32 * kk);
    }
    f32x4 dacc = {0.f, 0.f, 0.f, 0.f};
#pragma unroll
    for (int kk = 0; kk < 16; ++kk)
        dacc = __builtin_amdgcn_mfma_f32_16x16x32_bf16(afrag[kk], bfrag[kk], dacc, 0, 0, 0);

    float s = 0.f;
    if (irow < NC) {
        const int cbase = ct * 16 + g * 4;
#pragma unroll
        for (int rI = 0; rI < 4; ++rI) {
            const int j = cbase + rI;
            if (j < NC && j != irow) s += fexp2(dacc[rI] * LOG2E);
        }
    }
#pragma unroll
    for (int o = 1; o < 64; o <<= 1) s += __shfl_xor(s, o, 64);
    if (lane == 0) wsum[wid] = s;
    __syncthreads();
    if (t == 0)
        atomicAdd(buckets + ((blockIdx.x + 16 * blockIdx.y) & (NBUCKET - 1)) * 16,
                  wsum[0] + wsum[1] + wsum[2] + wsum[3]);
}

// ---------------- final combine: sum buckets ----------------
__global__ void combine_kernel(const float* __restrict__ a, float* __restrict__ out) {
    const int t = threadIdx.x;  // 64 threads
    float s = a[t * 16], c = a[1024 + t * 16], gr = a[2048 + t * 16];
#pragma unroll
    for (int o = 1; o < 64; o <<= 1) {
        s += __shfl_xor(s, o, 64);
        c += __shfl_xor(c, o, 64);
        gr += __shfl_xor(gr, o, 64);
    }
    if (t == 0) out[0] = s + c + logf(gr) * (1.0f / (float)NC);
}

extern "C" void kernel_launch(void* const* d_in, const int* in_sizes, int n_in,
                              void* d_out, int out_size, void* d_ws, size_t ws_size,
                              hipStream_t stream) {
    const float* feat   = (const float*)d_in[0];  // [32768,512]
    const float* logits = (const float*)d_in[1];  // [32768,1000]
    const int*   labels = (const int*)d_in[2];    // [32768]
    const float* pro    = (const float*)d_in[3];  // [1000,512]
    float* out = (float*)d_out;

    float* acc = (float*)d_ws;  // buckets: [0]=sim, [1024]=ce, [2048]=gram (stride-16 floats)
    unsigned short* pbf = (unsigned short*)((char*)d_ws + 16384);  // [1024][512] bf16, 1 MiB

    hipMemsetAsync(d_ws, 0, 3072 * sizeof(float), stream);
    hipLaunchKernelGGL(norm_protos,    dim3(PROWS),    dim3(256), 0, stream, pro, pbf);
    hipLaunchKernelGGL(simloss_kernel, dim3(NB / 128), dim3(256), 0, stream, feat, labels, pbf, acc);
    hipLaunchKernelGGL(ce_kernel,      dim3(1024),     dim3(256), 0, stream, logits, labels, acc + 1024);
    hipLaunchKernelGGL(gram_kernel,    dim3(16, 63),   dim3(256), 0, stream, pbf, acc + 2048);
    hipLaunchKernelGGL(combine_kernel, dim3(1),        dim3(64),  0, stream, acc, out);
}

// Round 5
// 101.165 us; speedup vs baseline: 1.7045x; 1.4607x over previous
//
#include <hip/hip_runtime.h>
#include <math.h>

#define NB 32768
#define NC 1000
#define ND 512
#define NTILES 63          // 63*16 = 1008 >= 1000 class columns
#define LOG2E 1.4426950408889634f
#define LN2 0.6931471805599453f
#define S2 14.426950408889634f   // (1/T) * log2(e)
#define NBUCKET 64

typedef __attribute__((ext_vector_type(8))) short short8;
typedef __attribute__((ext_vector_type(4))) float f32x4;

__device__ __forceinline__ float fexp2(float x) {
    float r; asm("v_exp_f32 %0, %1" : "=v"(r) : "v"(x)); return r;
}
__device__ __forceinline__ float flog2(float x) {
    float r; asm("v_log_f32 %0, %1" : "=v"(r) : "v"(x)); return r;
}
__device__ __forceinline__ unsigned short bf16_rne(float f) {
    unsigned int u = __builtin_bit_cast(unsigned int, f);
    u += 0x7FFFu + ((u >> 16) & 1u);
    return (unsigned short)(u >> 16);
}
__device__ __forceinline__ short8 pack8f(float4 a, float4 b) {
    short8 s;
    s[0] = (short)bf16_rne(a.x); s[1] = (short)bf16_rne(a.y);
    s[2] = (short)bf16_rne(a.z); s[3] = (short)bf16_rne(a.w);
    s[4] = (short)bf16_rne(b.x); s[5] = (short)bf16_rne(b.y);
    s[6] = (short)bf16_rne(b.z); s[7] = (short)bf16_rne(b.w);
    return s;
}

// ---------------- normalize prototypes -> bf16 in MFMA FRAGMENT ORDER ----------------
// frag[tile*1024 + kk*64 + g*16 + r] (short8 units) = row (tile*16+r), cols 32*kk+8*g..+8.
// A wave's A-operand load for (tile,kk) is then frag[tile*1024+kk*64+lane]: 1KB contiguous.
__global__ __launch_bounds__(256) void norm_protos(const float* __restrict__ pro,
                                                   unsigned short* __restrict__ pbf) {
    const int row = blockIdx.x, t = threadIdx.x;   // grid 1024 rows (>=NC padded w/ zeros)
    const int tile = row >> 4, r = row & 15;
    const int kk = t >> 4, g = (t >> 2) & 3, slot = t & 3;
    unsigned int* dst = (unsigned int*)pbf +
        ((size_t)tile * 1024 + kk * 64 + g * 16 + r) * 4 + slot;
    if (row >= NC) { *dst = 0u; return; }  // zero pad rows (uniform per block)
    const float* rp = pro + (size_t)row * ND;
    const float x0 = rp[2 * t], x1 = rp[2 * t + 1];
    float ss = x0 * x0 + x1 * x1;
#pragma unroll
    for (int o = 1; o < 64; o <<= 1) ss += __shfl_xor(ss, o, 64);
    __shared__ float part[4];
    if ((t & 63) == 0) part[t >> 6] = ss;
    __syncthreads();
    const float nrm = sqrtf(part[0] + part[1] + part[2] + part[3]);
    const float sc = 1.0f / fmaxf(nrm, 1e-12f);
    *dst = (unsigned int)bf16_rne(x0 * sc) | ((unsigned int)bf16_rne(x1 * sc) << 16);
}

// ---------------- fused simloss + cross-entropy ----------------
// Sim: 16x16x32 MFMA swapped operands, D layout (m89): col=lane&15=feature row,
// class=(lane>>4)*4+reg. Wave holds 32 feature rows; P tiles double-buffered in
// REGISTERS straight from L1/L2 (no LDS, no barriers in the hot loop).
#define TILE_BODY(P, CT)                                                            \
    do {                                                                            \
        f32x4 a0 = {0.f, 0.f, 0.f, 0.f}, a1 = {0.f, 0.f, 0.f, 0.f};                \
        _Pragma("unroll")                                                           \
        for (int kk = 0; kk < 16; ++kk) {                                           \
            a0 = __builtin_amdgcn_mfma_f32_16x16x32_bf16(P[kk], bf0[kk], a0, 0, 0, 0); \
            a1 = __builtin_amdgcn_mfma_f32_16x16x32_bf16(P[kk], bf1[kk], a1, 0, 0, 0); \
        }                                                                           \
        const int cbase = (CT) * 16 + g * 4;                                        \
        {                                                                           \
            float x[4];                                                            \
            _Pragma("unroll")                                                       \
            for (int rI = 0; rI < 4; ++rI) {                                        \
                const float v = a0[rI] * S2;                                        \
                x[rI] = (cbase + rI < NC) ? v : -INFINITY;                          \
                lv0 += (cbase + rI == lab0) ? v : 0.f;                              \
            }                                                                       \
            const float tmax = fmaxf(fmaxf(x[0], x[1]), fmaxf(x[2], x[3]));         \
            const float mn = fmaxf(m0, tmax);                                       \
            ls0 *= fexp2(m0 - mn);                                                  \
            m0 = mn;                                                                \
            ls0 += fexp2(x[0] - mn) + fexp2(x[1] - mn) + fexp2(x[2] - mn) + fexp2(x[3] - mn); \
        }                                                                           \
        {                                                                           \
            float x[4];                                                            \
            _Pragma("unroll")                                                       \
            for (int rI = 0; rI < 4; ++rI) {                                        \
                const float v = a1[rI] * S2;                                        \
                x[rI] = (cbase + rI < NC) ? v : -INFINITY;                          \
                lv1 += (cbase + rI == lab1) ? v : 0.f;                              \
            }                                                                       \
            const float tmax = fmaxf(fmaxf(x[0], x[1]), fmaxf(x[2], x[3]));         \
            const float mn = fmaxf(m1, tmax);                                       \
            ls1 *= fexp2(m1 - mn);                                                  \
            m1 = mn;                                                                \
            ls1 += fexp2(x[0] - mn) + fexp2(x[1] - mn) + fexp2(x[2] - mn) + fexp2(x[3] - mn); \
        }                                                                           \
    } while (0)

__global__ __launch_bounds__(256, 1) void main_kernel(const float* __restrict__ feat,
                                                      const float* __restrict__ logits,
                                                      const int* __restrict__ labels,
                                                      const unsigned short* __restrict__ pbf,
                                                      float* __restrict__ buckets) {
    __shared__ float wsum[4], wsumce[4];
    const int t = threadIdx.x;
    const int wid = t >> 6, lane = t & 63;
    const int r16 = lane & 15, g = lane >> 4;
    const int rowbase = blockIdx.x * 128 + wid * 32;
    const short8* frag = (const short8*)pbf;

    // P tile 0 into registers (issue first: overlaps feature-load latency)
    short8 PA[16], PB[16];
#pragma unroll
    for (int k = 0; k < 16; ++k) PA[k] = frag[k * 64 + lane];

    // Feature fragments for 2 row-groups: bf*[kk] = feat[row][32*kk + 8*g .. +8]
    short8 bf0[16], bf1[16];
    {
        const float* f0 = feat + (size_t)(rowbase + r16) * ND + 8 * g;
        const float* f1 = f0 + 16 * ND;
#pragma unroll
        for (int kk = 0; kk < 16; ++kk) {
            bf0[kk] = pack8f(*(const float4*)(f0 + 32 * kk), *(const float4*)(f0 + 32 * kk + 4));
            bf1[kk] = pack8f(*(const float4*)(f1 + 32 * kk), *(const float4*)(f1 + 32 * kk + 4));
        }
    }
    int lab0 = labels[rowbase + r16];
    int lab1 = labels[rowbase + 16 + r16];
    lab0 = lab0 < 0 ? 0 : (lab0 > NC - 1 ? NC - 1 : lab0);
    lab1 = lab1 < 0 ? 0 : (lab1 > NC - 1 ? NC - 1 : lab1);

    float m0 = -INFINITY, ls0 = 0.f, lv0 = 0.f;
    float m1 = -INFINITY, ls1 = 0.f, lv1 = 0.f;

    // 63 tiles: 31 double-buffered pairs + tail. No barriers; loads hide under MFMA+softmax.
#pragma unroll 1
    for (int ct = 0; ct < 62; ct += 2) {
#pragma unroll
        for (int k = 0; k < 16; ++k) PB[k] = frag[(ct + 1) * 1024 + k * 64 + lane];
        TILE_BODY(PA, ct);
#pragma unroll
        for (int k = 0; k < 16; ++k) PA[k] = frag[(ct + 2) * 1024 + k * 64 + lane];
        TILE_BODY(PB, ct + 1);
    }
    TILE_BODY(PA, 62);

    // Merge the 4 lane-groups (g=0..3) holding the same feature rows
#pragma unroll
    for (int o = 16; o <= 32; o <<= 1) {
        {
            const float mo = __shfl_xor(m0, o, 64), lo = __shfl_xor(ls0, o, 64);
            lv0 += __shfl_xor(lv0, o, 64);
            const float mm = fmaxf(m0, mo);
            ls0 = ls0 * fexp2(m0 - mm) + lo * fexp2(mo - mm);
            m0 = mm;
        }
        {
            const float mo = __shfl_xor(m1, o, 64), lo = __shfl_xor(ls1, o, 64);
            lv1 += __shfl_xor(lv1, o, 64);
            const float mm = fmaxf(m1, mo);
            ls1 = ls1 * fexp2(m1 - mm) + lo * fexp2(mo - mm);
            m1 = mm;
        }
    }
    const float row0 = (m0 + flog2(ls0) - lv0) * LN2;  // replicated on 4 lanes
    const float row1 = (m1 + flog2(ls1) - lv1) * LN2;
    float mine = (row0 + row1) * (1.0f / (4.0f * (float)NB));
#pragma unroll
    for (int o = 1; o < 64; o <<= 1) mine += __shfl_xor(mine, o, 64);

    // ---- CE phase: this wave handles its own 32 rows of logits ----
    float localce = 0.f;
#pragma unroll 1
    for (int i = 0; i < 32; ++i) {
        const int row = rowbase + i;
        const float* rp = logits + (size_t)row * NC;
        float x[16];
#pragma unroll
        for (int j = 0; j < 4; ++j) {
            const int c0 = lane * 4 + j * 256;
            if (c0 < NC) {
                const float4 v = *(const float4*)(rp + c0);
                x[4 * j] = v.x * LOG2E; x[4 * j + 1] = v.y * LOG2E;
                x[4 * j + 2] = v.z * LOG2E; x[4 * j + 3] = v.w * LOG2E;
            } else {
                x[4 * j] = x[4 * j + 1] = x[4 * j + 2] = x[4 * j + 3] = -INFINITY;
            }
        }
        float m = -INFINITY;
#pragma unroll
        for (int i2 = 0; i2 < 16; ++i2) m = fmaxf(m, x[i2]);
#pragma unroll
        for (int o = 1; o < 64; o <<= 1) m = fmaxf(m, __shfl_xor(m, o, 64));
        float s = 0.f;
#pragma unroll
        for (int i2 = 0; i2 < 16; ++i2) s += fexp2(x[i2] - m);
#pragma unroll
        for (int o = 1; o < 64; o <<= 1) s += __shfl_xor(s, o, 64);
        int lab = labels[row];
        lab = lab < 0 ? 0 : (lab > NC - 1 ? NC - 1 : lab);
        localce += (m + flog2(s)) * LN2 - rp[lab];  // identical on all lanes
    }

    if (lane == 0) { wsum[wid] = mine; wsumce[wid] = localce; }
    __syncthreads();
    if (t == 0) {
        const int b = (blockIdx.x & (NBUCKET - 1)) * 16;
        atomicAdd(buckets + b, wsum[0] + wsum[1] + wsum[2] + wsum[3]);
        atomicAdd(buckets + 1024 + b,
                  (wsumce[0] + wsumce[1] + wsumce[2] + wsumce[3]) * (1.0f / (float)NB));
    }
}

// ---------------- prototype Gram exp-sum (off-diagonal); frag-layout reads ----------------
__global__ __launch_bounds__(256) void gram_kernel(const unsigned short* __restrict__ pbf,
                                                   float* __restrict__ buckets) {
    __shared__ float wsum[4];
    const int t = threadIdx.x;
    const int wid = t >> 6, lane = t & 63;
    const int r16 = lane & 15, g = lane >> 4;
    const int ct = blockIdx.y;                    // class tile 0..62 (A side)
    const int btile = blockIdx.x * 4 + wid;       // feature-side tile 0..63 (pad zeros)
    const int irow = btile * 16 + r16;
    const short8* frag = (const short8*)pbf;

    short8 af[16], bf[16];
#pragma unroll
    for (int kk = 0; kk < 16; ++kk) {
        af[kk] = frag[(size_t)ct * 1024 + kk * 64 + lane];
        bf[kk] = frag[(size_t)btile * 1024 + kk * 64 + lane];
    }
    f32x4 dacc = {0.f, 0.f, 0.f, 0.f};
#pragma unroll
    for (int kk = 0; kk < 16; ++kk)
        dacc = __builtin_amdgcn_mfma_f32_16x16x32_bf16(af[kk], bf[kk], dacc, 0, 0, 0);

    float s = 0.f;
    if (irow < NC) {
        const int cbase = ct * 16 + g * 4;
#pragma unroll
        for (int rI = 0; rI < 4; ++rI) {
            const int j = cbase + rI;
            if (j < NC && j != irow) s += fexp2(dacc[rI] * LOG2E);
        }
    }
#pragma unroll
    for (int o = 1; o < 64; o <<= 1) s += __shfl_xor(s, o, 64);
    if (lane == 0) wsum[wid] = s;
    __syncthreads();
    if (t == 0)
        atomicAdd(buckets + ((blockIdx.x + 16 * blockIdx.y) & (NBUCKET - 1)) * 16,
                  wsum[0] + wsum[1] + wsum[2] + wsum[3]);
}

// ---------------- final combine: sum buckets ----------------
__global__ void combine_kernel(const float* __restrict__ a, float* __restrict__ out) {
    const int t = threadIdx.x;  // 64 threads
    float s = a[t * 16], c = a[1024 + t * 16], gr = a[2048 + t * 16];
#pragma unroll
    for (int o = 1; o < 64; o <<= 1) {
        s += __shfl_xor(s, o, 64);
        c += __shfl_xor(c, o, 64);
        gr += __shfl_xor(gr, o, 64);
    }
    if (t == 0) out[0] = s + c + logf(gr) * (1.0f / (float)NC);
}

extern "C" void kernel_launch(void* const* d_in, const int* in_sizes, int n_in,
                              void* d_out, int out_size, void* d_ws, size_t ws_size,
                              hipStream_t stream) {
    const float* feat   = (const float*)d_in[0];  // [32768,512]
    const float* logits = (const float*)d_in[1];  // [32768,1000]
    const int*   labels = (const int*)d_in[2];    // [32768]
    const float* pro    = (const float*)d_in[3];  // [1000,512]
    float* out = (float*)d_out;

    float* acc = (float*)d_ws;  // buckets: [0]=sim, [1024]=ce, [2048]=gram (stride-16 floats)
    unsigned short* pbf = (unsigned short*)((char*)d_ws + 16384);  // frag-order bf16, 1 MiB

    hipMemsetAsync(d_ws, 0, 3072 * sizeof(float), stream);
    hipLaunchKernelGGL(norm_protos,    dim3(1024),     dim3(256), 0, stream, pro, pbf);
    hipLaunchKernelGGL(main_kernel,    dim3(NB / 128), dim3(256), 0, stream, feat, logits, labels, pbf, acc);
    hipLaunchKernelGGL(gram_kernel,    dim3(16, 63),   dim3(256), 0, stream, pbf, acc + 2048);
    hipLaunchKernelGGL(combine_kernel, dim3(1),        dim3(64),  0, stream, acc, out);
}